// Round 2
// baseline (634.094 us; speedup 1.0000x reference)
//
#include <hip/hip_runtime.h>
#include <hip/hip_bf16.h>
#include <stdint.h>

// Problem constants
#define BB     8
#define CC     128
#define HW     9216      // 96*96
#define NHEAD  8
#define HD     64
#define NCH    16        // gram n-chunks
#define CHUNK  576       // HW/NCH

typedef __hip_bfloat16 bf16;

__device__ __forceinline__ float b2f(bf16 v) { return __bfloat162float(v); }
__device__ __forceinline__ bf16  f2b(float v) { return __float2bfloat16(v); }
__device__ __forceinline__ float us2f(unsigned short u) {
  return __uint_as_float(((unsigned int)u) << 16);
}

// ---------------------------------------------------------------- K1: qkv depthwise conv + q/k norm sums
// block = (b, c). conv out channel oc = c*12 + j; j in [0,4)=q(e=j), [4,8)=k, [8,12)=v.
// head h = e*2 + c/64, row d = c%64. Stores q,k,v bf16 as [b, h, d_or_e, n].
__global__ __launch_bounds__(256) void k1_qkv(
    const float* __restrict__ x, const float* __restrict__ wq,
    const float* __restrict__ bq,
    bf16* __restrict__ qg, bf16* __restrict__ kg, bf16* __restrict__ vg,
    float* __restrict__ qn2, float* __restrict__ kn2) {
  __shared__ float xs[HW];
  __shared__ float red[256];
  int tid = threadIdx.x;
  int b = blockIdx.x >> 7, c = blockIdx.x & 127;
  const float* xp = x + (size_t)(b * CC + c) * HW;
  for (int i = tid; i < HW / 4; i += 256)
    ((float4*)xs)[i] = ((const float4*)xp)[i];
  __syncthreads();

  int half = c >> 6, d = c & 63;
  int nidx[8];
  size_t basep[12];
#pragma unroll
  for (int j = 0; j < 12; ++j) {
    int e = j & 3;                       // j%4 within each q/k/v group
    int h = e * 2 + half;
    int ni = (b * NHEAD + h) * HD + d;
    if (j < 8) nidx[j] = ni;
    basep[j] = (size_t)ni * HW;
  }
  const float* wrow = wq + c * 108;      // 12 channels * 9 taps, uniform -> s_load
  const float* brow = bq + c * 12;

  float ssq[8];
#pragma unroll
  for (int j = 0; j < 8; ++j) ssq[j] = 0.f;

  for (int p = tid; p < HW; p += 256) {
    int y = p / 96, xx = p - y * 96;
    float nb[9];
#pragma unroll
    for (int ky = 0; ky < 3; ++ky)
#pragma unroll
      for (int kx = 0; kx < 3; ++kx) {
        int yy = y + ky - 1, xc = xx + kx - 1;
        nb[ky * 3 + kx] =
            (yy >= 0 && yy < 96 && xc >= 0 && xc < 96) ? xs[yy * 96 + xc] : 0.f;
      }
#pragma unroll
    for (int j = 0; j < 12; ++j) {
      float acc = brow[j];
#pragma unroll
      for (int i = 0; i < 9; ++i) acc = fmaf(wrow[j * 9 + i], nb[i], acc);
      bf16 hv = f2b(acc);
      float av = b2f(hv);               // norm from the rounded value (consistent with gram)
      if (j < 4)      { qg[basep[j] + p] = hv; ssq[j] += av * av; }
      else if (j < 8) { kg[basep[j] + p] = hv; ssq[j] += av * av; }
      else            { vg[basep[j] + p] = hv; }
    }
  }
  // block-reduce the 8 sum-of-squares (4 q rows, 4 k rows owned exclusively by this block)
  for (int j = 0; j < 8; ++j) {
    __syncthreads();
    red[tid] = ssq[j];
    __syncthreads();
    for (int s = 128; s > 0; s >>= 1) {
      if (tid < s) red[tid] += red[tid + s];
      __syncthreads();
    }
    if (tid == 0) {
      if (j < 4) qn2[nidx[j]] = red[0];
      else       kn2[nidx[j]] = red[0];
    }
  }
}

// ---------------------------------------------------------------- K2a: gram partials  part[bh][chunk][d][e]
// block = (chunk, bh); 256 threads each own a 4x4 (d,e) sub-tile.
__global__ __launch_bounds__(256) void k2_gram(
    const bf16* __restrict__ qg, const bf16* __restrict__ kg,
    float* __restrict__ part) {
  __shared__ float qt[16][72];   // [nn][d], padded stride 72 (16B aligned, bank phase 8)
  __shared__ float kt[16][72];
  int tid = threadIdx.x;
  int chunk = blockIdx.x;        // 0..15
  int bh = blockIdx.y;           // 0..63
  int dt = tid >> 4, et = tid & 15;
  int d0 = dt * 4, e0 = et * 4;
  float acc[16];
#pragma unroll
  for (int i = 0; i < 16; ++i) acc[i] = 0.f;

  int row = tid >> 2;            // 0..63
  int nn0 = (tid & 3) * 4;       // 0,4,8,12
  const size_t base = (size_t)bh * HD * HW;

  for (int t = 0; t < 36; ++t) {          // 36 tiles of 16 pixels
    int nb = chunk * CHUNK + t * 16;
    __syncthreads();
    ushort4 q4 = *(const ushort4*)(qg + base + (size_t)row * HW + nb + nn0);
    ushort4 k4 = *(const ushort4*)(kg + base + (size_t)row * HW + nb + nn0);
    qt[nn0 + 0][row] = us2f(q4.x); qt[nn0 + 1][row] = us2f(q4.y);
    qt[nn0 + 2][row] = us2f(q4.z); qt[nn0 + 3][row] = us2f(q4.w);
    kt[nn0 + 0][row] = us2f(k4.x); kt[nn0 + 1][row] = us2f(k4.y);
    kt[nn0 + 2][row] = us2f(k4.z); kt[nn0 + 3][row] = us2f(k4.w);
    __syncthreads();
#pragma unroll
    for (int nn = 0; nn < 16; ++nn) {
      float4 qv = *(const float4*)&qt[nn][d0];
      float4 kv = *(const float4*)&kt[nn][e0];
      acc[0]  = fmaf(qv.x, kv.x, acc[0]);  acc[1]  = fmaf(qv.x, kv.y, acc[1]);
      acc[2]  = fmaf(qv.x, kv.z, acc[2]);  acc[3]  = fmaf(qv.x, kv.w, acc[3]);
      acc[4]  = fmaf(qv.y, kv.x, acc[4]);  acc[5]  = fmaf(qv.y, kv.y, acc[5]);
      acc[6]  = fmaf(qv.y, kv.z, acc[6]);  acc[7]  = fmaf(qv.y, kv.w, acc[7]);
      acc[8]  = fmaf(qv.z, kv.x, acc[8]);  acc[9]  = fmaf(qv.z, kv.y, acc[9]);
      acc[10] = fmaf(qv.z, kv.z, acc[10]); acc[11] = fmaf(qv.z, kv.w, acc[11]);
      acc[12] = fmaf(qv.w, kv.x, acc[12]); acc[13] = fmaf(qv.w, kv.y, acc[13]);
      acc[14] = fmaf(qv.w, kv.z, acc[14]); acc[15] = fmaf(qv.w, kv.w, acc[15]);
    }
  }
  float* po = part + (size_t)(bh * NCH + chunk) * 4096;
#pragma unroll
  for (int i = 0; i < 4; ++i) {
    *(float4*)&po[(d0 + i) * 64 + e0] =
        make_float4(acc[i * 4 + 0], acc[i * 4 + 1], acc[i * 4 + 2], acc[i * 4 + 3]);
  }
}

// ---------------------------------------------------------------- K2r: reduce partials -> gram
__global__ void k2_reduce(const float* __restrict__ part, float* __restrict__ gram) {
  int idx = blockIdx.x * 256 + threadIdx.x;   // < 64*4096
  int bh = idx >> 12, de = idx & 4095;
  float s = 0.f;
#pragma unroll
  for (int ch = 0; ch < NCH; ++ch)
    s += part[(size_t)(bh * NCH + ch) * 4096 + de];
  gram[idx] = s;
}

// ---------------------------------------------------------------- K2b: normalize + softmax, write TRANSPOSED copy
// attnT[bh][e][d] = softmax_e( gram[d][e]*t[h]/(|q_d||k_e|) )
__global__ __launch_bounds__(64) void k2_softmax(
    const float* __restrict__ gram, float* __restrict__ attnT,
    const float* __restrict__ qn2, const float* __restrict__ kn2,
    const float* __restrict__ t_f) {
  __shared__ float kns[64];
  int bh = blockIdx.x, d = threadIdx.x;
  const size_t base = (size_t)bh * 4096;
  kns[d] = fmaxf(sqrtf(kn2[bh * 64 + d]), 1e-12f);
  __syncthreads();
  float qn = fmaxf(sqrtf(qn2[bh * 64 + d]), 1e-12f);
  float sc = t_f[bh & 7] / qn;
  float lg[64];
  float m = -1e30f;
#pragma unroll
  for (int e = 0; e < 64; ++e) {
    lg[e] = gram[base + d * 64 + e] * sc / kns[e];
    m = fmaxf(m, lg[e]);
  }
  float s = 0.f;
#pragma unroll
  for (int e = 0; e < 64; ++e) { lg[e] = __expf(lg[e] - m); s += lg[e]; }
  float inv = 1.f / s;
#pragma unroll
  for (int e = 0; e < 64; ++e) attnT[base + e * 64 + d] = lg[e] * inv;
}

// ---------------------------------------------------------------- K3: o = attn @ v, stored in fused-conv layout
// o channel cc = ((h&1)*64 + d)*4 + (h>>1). attnT read: row e contiguous over d, wave-uniform.
__global__ __launch_bounds__(256) void k3_av(
    const float* __restrict__ attnT, const bf16* __restrict__ vg,
    bf16* __restrict__ og) {
  int tid = threadIdx.x;
  int chunk = blockIdx.x;   // 0..8 (1024 pixels each)
  int bh = blockIdx.y;      // 0..63
  int b = bh >> 3, h = bh & 7;
  const float* at = attnT + (size_t)bh * 4096;
  const bf16* vp = vg + (size_t)bh * HD * HW;
  int cc0 = (h & 1) * 256 + (h >> 1);
  bf16* ob = og + (size_t)b * 512 * HW;
  for (int pp = 0; pp < 4; ++pp) {
    int n = chunk * 1024 + pp * 256 + tid;
    float acc[64];
#pragma unroll
    for (int i = 0; i < 64; ++i) acc[i] = 0.f;
    for (int e = 0; e < 64; ++e) {
      float vv = b2f(vp[(size_t)e * HW + n]);
      const float* ar = at + e * 64;    // attn[d][e] over d, uniform -> SGPR operands
#pragma unroll
      for (int dd = 0; dd < 64; ++dd) acc[dd] = fmaf(ar[dd], vv, acc[dd]);
    }
#pragma unroll
    for (int dd = 0; dd < 64; ++dd)
      ob[(size_t)(cc0 + dd * 4) * HW + n] = f2b(acc[dd]);
  }
}

// ---------------------------------------------------------------- K4: fused grouped 3x3 conv (4 in-ch -> 1 out-ch)
__global__ __launch_bounds__(256) void k4_fuse(
    const bf16* __restrict__ og, const float* __restrict__ wf,
    const float* __restrict__ bfu, float* __restrict__ out) {
  int tid = threadIdx.x;
  int b = blockIdx.x >> 7, c = blockIdx.x & 127;
  const bf16* op = og + (size_t)(b * 512 + c * 4) * HW;
  const float* wrow = wf + c * 36;
  float bias = bfu[c];
  float* outp = out + (size_t)(b * CC + c) * HW;
  for (int p = tid; p < HW; p += 256) {
    int y = p / 96, xx = p - y * 96;
    float acc = bias;
#pragma unroll
    for (int e = 0; e < 4; ++e)
#pragma unroll
      for (int ky = 0; ky < 3; ++ky) {
        int yy = y + ky - 1;
#pragma unroll
        for (int kx = 0; kx < 3; ++kx) {
          int xc = xx + kx - 1;
          float ov = (yy >= 0 && yy < 96 && xc >= 0 && xc < 96)
                         ? b2f(op[(size_t)e * HW + yy * 96 + xc]) : 0.f;
          acc = fmaf(wrow[e * 9 + ky * 3 + kx], ov, acc);
        }
      }
    outp[p] = acc;
  }
}

// ---------------------------------------------------------------- launcher
extern "C" void kernel_launch(void* const* d_in, const int* in_sizes, int n_in,
                              void* d_out, int out_size, void* d_ws, size_t ws_size,
                              hipStream_t stream) {
  (void)in_sizes; (void)n_in; (void)out_size; (void)ws_size;
  const float* x   = (const float*)d_in[0];
  const float* wq  = (const float*)d_in[1];
  const float* bq  = (const float*)d_in[2];
  const float* tt  = (const float*)d_in[3];
  const float* wf  = (const float*)d_in[4];
  const float* bfu = (const float*)d_in[5];

  // workspace layout (~234 MB)
  char* ws = (char*)d_ws;
  bf16*  qg    = (bf16*)(ws + 0);                 // 75497472 B, later aliased by og
  bf16*  kg    = (bf16*)(ws + 75497472);          // 75497472 B
  bf16*  vg    = (bf16*)(ws + 150994944);         // 75497472 B
  float* part  = (float*)(ws + 226492416);        // 16777216 B
  float* gram  = (float*)(ws + 243269632);        // 1048576 B
  float* attnT = (float*)(ws + 244318208);        // 1048576 B
  float* qn2   = (float*)(ws + 245366784);        // 16384 B
  float* kn2   = (float*)(ws + 245383168);        // 16384 B
  bf16*  og    = qg;                              // q is dead after k2_gram
  float* out   = (float*)d_out;

  hipLaunchKernelGGL(k1_qkv, dim3(1024), dim3(256), 0, stream,
                     x, wq, bq, qg, kg, vg, qn2, kn2);
  hipLaunchKernelGGL(k2_gram, dim3(NCH, 64), dim3(256), 0, stream, qg, kg, part);
  hipLaunchKernelGGL(k2_reduce, dim3(1024), dim3(256), 0, stream, part, gram);
  hipLaunchKernelGGL(k2_softmax, dim3(64), dim3(64), 0, stream,
                     gram, attnT, qn2, kn2, tt);
  hipLaunchKernelGGL(k3_av, dim3(9, 64), dim3(256), 0, stream, attnT, vg, og);
  hipLaunchKernelGGL(k4_fuse, dim3(1024), dim3(256), 0, stream, og, wf, bfu, out);
}

// Round 3
// 393.128 us; speedup vs baseline: 1.6129x; 1.6129x over previous
//
#include <hip/hip_runtime.h>
#include <hip/hip_bf16.h>
#include <stdint.h>

// Problem constants
#define BB     8
#define CC     128
#define HW     9216      // 96*96
#define NHEAD  8
#define HD     64
#define NCH    16        // gram n-chunks
#define CHUNK  576       // HW/NCH

typedef __hip_bfloat16 bf16;
using frag16 = __attribute__((ext_vector_type(8))) short;  // 8 bf16 (4 VGPRs)
using f32x4  = __attribute__((ext_vector_type(4))) float;

__device__ __forceinline__ float b2f(bf16 v) { return __bfloat162float(v); }
__device__ __forceinline__ bf16  f2b(float v) { return __float2bfloat16(v); }

// ---------------------------------------------------------------- K1: qkv depthwise conv + q/k norm sums
// block = (b, c). conv out channel oc = c*12 + j; j in [0,4)=q(e=j), [4,8)=k, [8,12)=v.
// head h = e*2 + c/64, row d = c%64. Stores q,k,v bf16 as [b, h, d_or_e, n].
// x staged in zero-padded LDS (rows 98, stride 104, interior col base 4) -> no bounds checks.
__global__ __launch_bounds__(256) void k1_qkv(
    const float* __restrict__ x, const float* __restrict__ wq,
    const float* __restrict__ bq,
    bf16* __restrict__ qg, bf16* __restrict__ kg, bf16* __restrict__ vg,
    float* __restrict__ qn2, float* __restrict__ kn2) {
  __shared__ float xs[98 * 104];    // 40.8 KB, zero-padded halo
  __shared__ float red[256];
  int tid = threadIdx.x;
  int b = blockIdx.x >> 7, c = blockIdx.x & 127;
  const float* xp = x + (size_t)(b * CC + c) * HW;
  // zero everything (covers borders), then fill interior
  for (int i = tid; i < (98 * 104) / 4; i += 256)
    ((float4*)xs)[i] = make_float4(0.f, 0.f, 0.f, 0.f);
  __syncthreads();
  for (int i = tid; i < 96 * 24; i += 256) {
    int y = i / 24, k4i = i - y * 24;
    ((float4*)(xs + (y + 1) * 104 + 4))[k4i] = ((const float4*)(xp + y * 96))[k4i];
  }
  __syncthreads();

  int half = c >> 6, d = c & 63;
  int nidx[8];
  size_t basep[12];
#pragma unroll
  for (int j = 0; j < 12; ++j) {
    int e = j & 3;                       // j%4 within each q/k/v group
    int h = e * 2 + half;
    int ni = (b * NHEAD + h) * HD + d;
    if (j < 8) nidx[j] = ni;
    basep[j] = (size_t)ni * HW;
  }
  const float* wrow = wq + c * 108;      // 12 channels * 9 taps, uniform -> s_load
  const float* brow = bq + c * 12;

  float ssq[8];
#pragma unroll
  for (int j = 0; j < 8; ++j) ssq[j] = 0.f;

  for (int p = tid; p < HW; p += 256) {
    int y = p / 96, xx = p - y * 96;
    float nb[9];
#pragma unroll
    for (int ky = 0; ky < 3; ++ky)
#pragma unroll
      for (int kx = 0; kx < 3; ++kx)
        nb[ky * 3 + kx] = xs[(y + ky) * 104 + 3 + xx + kx];
#pragma unroll
    for (int j = 0; j < 12; ++j) {
      float acc = brow[j];
#pragma unroll
      for (int i = 0; i < 9; ++i) acc = fmaf(wrow[j * 9 + i], nb[i], acc);
      bf16 hv = f2b(acc);
      float av = b2f(hv);               // norm from the rounded value (consistent with gram)
      if (j < 4)      { qg[basep[j] + p] = hv; ssq[j] += av * av; }
      else if (j < 8) { kg[basep[j] + p] = hv; ssq[j] += av * av; }
      else            { vg[basep[j] + p] = hv; }
    }
  }
  // block-reduce the 8 sum-of-squares (4 q rows, 4 k rows owned exclusively by this block)
  for (int j = 0; j < 8; ++j) {
    __syncthreads();
    red[tid] = ssq[j];
    __syncthreads();
    for (int s = 128; s > 0; s >>= 1) {
      if (tid < s) red[tid] += red[tid + s];
      __syncthreads();
    }
    if (tid == 0) {
      if (j < 4) qn2[nidx[j]] = red[0];
      else       kn2[nidx[j]] = red[0];
    }
  }
}

// ---------------------------------------------------------------- K2a: gram partials via MFMA
// part[bh][chunk][d][e] += q[d][n]*k[e][n] over the chunk. A=qg rows, B^T=kg rows.
// wave w owns d-tile w; 4 e-tiles per wave. Frag: lane holds row (lane&15), k-off (lane>>4)*8.
__global__ __launch_bounds__(256) void k2_gram(
    const bf16* __restrict__ qg, const bf16* __restrict__ kg,
    float* __restrict__ part) {
  int tid = threadIdx.x;
  int wave = tid >> 6;           // 0..3 -> d-tile
  int lane = tid & 63;
  int chunk = blockIdx.x;        // 0..15
  int bh = blockIdx.y;           // 0..63
  const size_t base = (size_t)bh * HD * HW;
  int m = lane & 15;
  int k8 = (lane >> 4) * 8;
  const bf16* qrow  = qg + base + (size_t)(wave * 16 + m) * HW + k8;
  const bf16* krow0 = kg + base + (size_t)m * HW + k8;
  f32x4 acc0 = {0.f, 0.f, 0.f, 0.f}, acc1 = acc0, acc2 = acc0, acc3 = acc0;
  for (int kb = 0; kb < CHUNK; kb += 32) {
    int off = chunk * CHUNK + kb;
    frag16 a  = *(const frag16*)(qrow + off);
    frag16 b0 = *(const frag16*)(krow0 + off);
    frag16 b1 = *(const frag16*)(krow0 + (size_t)16 * HW + off);
    frag16 b2 = *(const frag16*)(krow0 + (size_t)32 * HW + off);
    frag16 b3 = *(const frag16*)(krow0 + (size_t)48 * HW + off);
    acc0 = __builtin_amdgcn_mfma_f32_16x16x32_bf16(a, b0, acc0, 0, 0, 0);
    acc1 = __builtin_amdgcn_mfma_f32_16x16x32_bf16(a, b1, acc1, 0, 0, 0);
    acc2 = __builtin_amdgcn_mfma_f32_16x16x32_bf16(a, b2, acc2, 0, 0, 0);
    acc3 = __builtin_amdgcn_mfma_f32_16x16x32_bf16(a, b3, acc3, 0, 0, 0);
  }
  // C/D layout: row(d) = (lane>>4)*4 + r, col(e) = lane&15
  float* po = part + (size_t)(bh * NCH + chunk) * 4096;
  int dr = wave * 16 + (lane >> 4) * 4;
  int e0 = lane & 15;
#pragma unroll
  for (int r = 0; r < 4; ++r) {
    po[(dr + r) * 64 +  0 + e0] = acc0[r];
    po[(dr + r) * 64 + 16 + e0] = acc1[r];
    po[(dr + r) * 64 + 32 + e0] = acc2[r];
    po[(dr + r) * 64 + 48 + e0] = acc3[r];
  }
}

// ---------------------------------------------------------------- K2r: reduce partials -> gram
__global__ void k2_reduce(const float* __restrict__ part, float* __restrict__ gram) {
  int idx = blockIdx.x * 256 + threadIdx.x;   // < 64*4096
  int bh = idx >> 12, de = idx & 4095;
  float s = 0.f;
#pragma unroll
  for (int ch = 0; ch < NCH; ++ch)
    s += part[(size_t)(bh * NCH + ch) * 4096 + de];
  gram[idx] = s;
}

// ---------------------------------------------------------------- K2b: normalize + softmax, write TRANSPOSED copy
// attnT[bh][e][d] = softmax_e( gram[d][e]*t[h]/(|q_d||k_e|) )
__global__ __launch_bounds__(64) void k2_softmax(
    const float* __restrict__ gram, float* __restrict__ attnT,
    const float* __restrict__ qn2, const float* __restrict__ kn2,
    const float* __restrict__ t_f) {
  __shared__ float kns[64];
  int bh = blockIdx.x, d = threadIdx.x;
  const size_t base = (size_t)bh * 4096;
  kns[d] = fmaxf(sqrtf(kn2[bh * 64 + d]), 1e-12f);
  __syncthreads();
  float qn = fmaxf(sqrtf(qn2[bh * 64 + d]), 1e-12f);
  float sc = t_f[bh & 7] / qn;
  float lg[64];
  float m = -1e30f;
#pragma unroll
  for (int e = 0; e < 64; ++e) {
    lg[e] = gram[base + d * 64 + e] * sc / kns[e];
    m = fmaxf(m, lg[e]);
  }
  float s = 0.f;
#pragma unroll
  for (int e = 0; e < 64; ++e) { lg[e] = __expf(lg[e] - m); s += lg[e]; }
  float inv = 1.f / s;
#pragma unroll
  for (int e = 0; e < 64; ++e) attnT[base + e * 64 + d] = lg[e] * inv;
}

// ---------------------------------------------------------------- K3: o = attn @ v, stored in fused-conv layout
// o channel cc = ((h&1)*64 + d)*4 + (h>>1). attnT read: row e contiguous over d, wave-uniform.
__global__ __launch_bounds__(256) void k3_av(
    const float* __restrict__ attnT, const bf16* __restrict__ vg,
    bf16* __restrict__ og) {
  int tid = threadIdx.x;
  int chunk = blockIdx.x;   // 0..8 (1024 pixels each)
  int bh = blockIdx.y;      // 0..63
  int b = bh >> 3, h = bh & 7;
  const float* at = attnT + (size_t)bh * 4096;
  const bf16* vp = vg + (size_t)bh * HD * HW;
  int cc0 = (h & 1) * 256 + (h >> 1);
  bf16* ob = og + (size_t)b * 512 * HW;
  for (int pp = 0; pp < 4; ++pp) {
    int n = chunk * 1024 + pp * 256 + tid;
    float acc[64];
#pragma unroll
    for (int i = 0; i < 64; ++i) acc[i] = 0.f;
    for (int e = 0; e < 64; ++e) {
      float vv = b2f(vp[(size_t)e * HW + n]);
      const float* ar = at + e * 64;    // attn[d][e] over d, uniform -> SGPR operands
#pragma unroll
      for (int dd = 0; dd < 64; ++dd) acc[dd] = fmaf(ar[dd], vv, acc[dd]);
    }
#pragma unroll
    for (int dd = 0; dd < 64; ++dd)
      ob[(size_t)(cc0 + dd * 4) * HW + n] = f2b(acc[dd]);
  }
}

// ---------------------------------------------------------------- K4: fused grouped 3x3 conv (4 in-ch -> 1 out-ch)
// Tile = 24 rows. All 4 input channels staged channel-interleaved into zero-padded LDS:
// lds[row 26][col 100][ch 4]; interior col base 2. Inner loop: 9 ds_read_b128 + 36 FMA, no branches.
__global__ __launch_bounds__(256) void k4_fuse(
    const bf16* __restrict__ og, const float* __restrict__ wf,
    const float* __restrict__ bfu, float* __restrict__ out) {
  __shared__ float lds[26 * 100 * 4];   // 41.6 KB
  int tid = threadIdx.x;
  int tile = blockIdx.x;                // 0..3
  int bc = blockIdx.y;                  // 0..1023
  int b = bc >> 7, c = bc & 127;
  for (int i = tid; i < (26 * 100 * 4) / 4; i += 256)
    ((float4*)lds)[i] = make_float4(0.f, 0.f, 0.f, 0.f);
  __syncthreads();
  int r0 = tile * 24 - 1;
  const bf16* op = og + (size_t)(b * 512 + c * 4) * HW;
  for (int i = tid; i < 26 * 96; i += 256) {
    int rr = i / 96, x = i - rr * 96;
    int gr = r0 + rr;
    if (gr >= 0 && gr < 96) {
      int gp = gr * 96 + x;
      float4 vv;
      vv.x = b2f(op[gp]);
      vv.y = b2f(op[HW + gp]);
      vv.z = b2f(op[2 * HW + gp]);
      vv.w = b2f(op[(size_t)3 * HW + gp]);
      *(float4*)&lds[(rr * 100 + 2 + x) * 4] = vv;
    }
  }
  __syncthreads();
  const float* wrow = wf + c * 36;      // uniform -> s_load
  float bias = bfu[c];
  float* outp = out + (size_t)(b * CC + c) * HW + tile * 24 * 96;
#pragma unroll
  for (int pi = 0; pi < 9; ++pi) {
    int p = pi * 256 + tid;
    int ry = p / 96, x = p - ry * 96;
    float a0 = bias, a1 = 0.f, a2 = 0.f, a3 = 0.f;
#pragma unroll
    for (int ky = 0; ky < 3; ++ky)
#pragma unroll
      for (int kx = 0; kx < 3; ++kx) {
        const float4 vv = *(const float4*)&lds[((ry + ky) * 100 + 1 + x + kx) * 4];
        a0 = fmaf(wrow[0 + ky * 3 + kx],  vv.x, a0);
        a1 = fmaf(wrow[9 + ky * 3 + kx],  vv.y, a1);
        a2 = fmaf(wrow[18 + ky * 3 + kx], vv.z, a2);
        a3 = fmaf(wrow[27 + ky * 3 + kx], vv.w, a3);
      }
    outp[p] = (a0 + a1) + (a2 + a3);
  }
}

// ---------------------------------------------------------------- launcher
extern "C" void kernel_launch(void* const* d_in, const int* in_sizes, int n_in,
                              void* d_out, int out_size, void* d_ws, size_t ws_size,
                              hipStream_t stream) {
  (void)in_sizes; (void)n_in; (void)out_size; (void)ws_size;
  const float* x   = (const float*)d_in[0];
  const float* wq  = (const float*)d_in[1];
  const float* bq  = (const float*)d_in[2];
  const float* tt  = (const float*)d_in[3];
  const float* wf  = (const float*)d_in[4];
  const float* bfu = (const float*)d_in[5];

  // workspace layout (~234 MB)
  char* ws = (char*)d_ws;
  bf16*  qg    = (bf16*)(ws + 0);                 // 75497472 B, later aliased by og
  bf16*  kg    = (bf16*)(ws + 75497472);          // 75497472 B
  bf16*  vg    = (bf16*)(ws + 150994944);         // 75497472 B
  float* part  = (float*)(ws + 226492416);        // 16777216 B
  float* gram  = (float*)(ws + 243269632);        // 1048576 B
  float* attnT = (float*)(ws + 244318208);        // 1048576 B
  float* qn2   = (float*)(ws + 245366784);        // 16384 B
  float* kn2   = (float*)(ws + 245383168);        // 16384 B
  bf16*  og    = qg;                              // q is dead after k2_gram
  float* out   = (float*)d_out;

  hipLaunchKernelGGL(k1_qkv, dim3(1024), dim3(256), 0, stream,
                     x, wq, bq, qg, kg, vg, qn2, kn2);
  hipLaunchKernelGGL(k2_gram, dim3(NCH, 64), dim3(256), 0, stream, qg, kg, part);
  hipLaunchKernelGGL(k2_reduce, dim3(1024), dim3(256), 0, stream, part, gram);
  hipLaunchKernelGGL(k2_softmax, dim3(64), dim3(64), 0, stream,
                     gram, attnT, qn2, kn2, tt);
  hipLaunchKernelGGL(k3_av, dim3(9, 64), dim3(256), 0, stream, attnT, vg, og);
  hipLaunchKernelGGL(k4_fuse, dim3(4, 1024), dim3(256), 0, stream, og, wf, bfu, out);
}

// Round 4
// 331.064 us; speedup vs baseline: 1.9153x; 1.1875x over previous
//
#include <hip/hip_runtime.h>
#include <hip/hip_bf16.h>
#include <stdint.h>

// Problem constants
#define BB     8
#define CC     128
#define HW     9216      // 96*96
#define NHEAD  8
#define HD     64
#define NCH    16        // gram n-chunks
#define CHUNK  576       // HW/NCH

typedef __hip_bfloat16 bf16;
using frag16 = __attribute__((ext_vector_type(8))) short;  // 8 bf16 (4 VGPRs)
using f32x4  = __attribute__((ext_vector_type(4))) float;

__device__ __forceinline__ float b2f(bf16 v) { return __bfloat162float(v); }
__device__ __forceinline__ bf16  f2b(float v) { return __float2bfloat16(v); }

// ---------------------------------------------------------------- K1: qkv depthwise conv + q/k norm sums
// block = (b, c). conv out channel oc = c*12 + j; j in [0,4)=q(e=j), [4,8)=k, [8,12)=v.
// head h = e*2 + c/64, row d = c%64. Stores q,k,v bf16 as [b, h, d_or_e, n].
// x staged in zero-padded LDS (rows 98, stride 104, interior col base 4) -> no bounds checks.
__global__ __launch_bounds__(256) void k1_qkv(
    const float* __restrict__ x, const float* __restrict__ wq,
    const float* __restrict__ bq,
    bf16* __restrict__ qg, bf16* __restrict__ kg, bf16* __restrict__ vg,
    float* __restrict__ qn2, float* __restrict__ kn2) {
  __shared__ float xs[98 * 104];    // 40.8 KB, zero-padded halo
  __shared__ float red[256];
  int tid = threadIdx.x;
  int b = blockIdx.x >> 7, c = blockIdx.x & 127;
  const float* xp = x + (size_t)(b * CC + c) * HW;
  // zero everything (covers borders), then fill interior
  for (int i = tid; i < (98 * 104) / 4; i += 256)
    ((float4*)xs)[i] = make_float4(0.f, 0.f, 0.f, 0.f);
  __syncthreads();
  for (int i = tid; i < 96 * 24; i += 256) {
    int y = i / 24, k4i = i - y * 24;
    ((float4*)(xs + (y + 1) * 104 + 4))[k4i] = ((const float4*)(xp + y * 96))[k4i];
  }
  __syncthreads();

  int half = c >> 6, d = c & 63;
  int nidx[8];
  size_t basep[12];
#pragma unroll
  for (int j = 0; j < 12; ++j) {
    int e = j & 3;                       // j%4 within each q/k/v group
    int h = e * 2 + half;
    int ni = (b * NHEAD + h) * HD + d;
    if (j < 8) nidx[j] = ni;
    basep[j] = (size_t)ni * HW;
  }
  const float* wrow = wq + c * 108;      // 12 channels * 9 taps, uniform -> s_load
  const float* brow = bq + c * 12;

  float ssq[8];
#pragma unroll
  for (int j = 0; j < 8; ++j) ssq[j] = 0.f;

  for (int p = tid; p < HW; p += 256) {
    int y = p / 96, xx = p - y * 96;
    float nb[9];
#pragma unroll
    for (int ky = 0; ky < 3; ++ky)
#pragma unroll
      for (int kx = 0; kx < 3; ++kx)
        nb[ky * 3 + kx] = xs[(y + ky) * 104 + 3 + xx + kx];
#pragma unroll
    for (int j = 0; j < 12; ++j) {
      float acc = brow[j];
#pragma unroll
      for (int i = 0; i < 9; ++i) acc = fmaf(wrow[j * 9 + i], nb[i], acc);
      bf16 hv = f2b(acc);
      float av = b2f(hv);               // norm from the rounded value (consistent with gram)
      if (j < 4)      { qg[basep[j] + p] = hv; ssq[j] += av * av; }
      else if (j < 8) { kg[basep[j] + p] = hv; ssq[j] += av * av; }
      else            { vg[basep[j] + p] = hv; }
    }
  }
  // block-reduce the 8 sum-of-squares (4 q rows, 4 k rows owned exclusively by this block)
  for (int j = 0; j < 8; ++j) {
    __syncthreads();
    red[tid] = ssq[j];
    __syncthreads();
    for (int s = 128; s > 0; s >>= 1) {
      if (tid < s) red[tid] += red[tid + s];
      __syncthreads();
    }
    if (tid == 0) {
      if (j < 4) qn2[nidx[j]] = red[0];
      else       kn2[nidx[j]] = red[0];
    }
  }
}

// ---------------------------------------------------------------- K2a: gram partials via MFMA
// part[bh][chunk][d][e] += q[d][n]*k[e][n] over the chunk. A=qg rows, B^T=kg rows.
__global__ __launch_bounds__(256) void k2_gram(
    const bf16* __restrict__ qg, const bf16* __restrict__ kg,
    float* __restrict__ part) {
  int tid = threadIdx.x;
  int wave = tid >> 6;           // 0..3 -> d-tile
  int lane = tid & 63;
  int chunk = blockIdx.x;        // 0..15
  int bh = blockIdx.y;           // 0..63
  const size_t base = (size_t)bh * HD * HW;
  int m = lane & 15;
  int k8 = (lane >> 4) * 8;
  const bf16* qrow  = qg + base + (size_t)(wave * 16 + m) * HW + k8;
  const bf16* krow0 = kg + base + (size_t)m * HW + k8;
  f32x4 acc0 = {0.f, 0.f, 0.f, 0.f}, acc1 = acc0, acc2 = acc0, acc3 = acc0;
  for (int kb = 0; kb < CHUNK; kb += 32) {
    int off = chunk * CHUNK + kb;
    frag16 a  = *(const frag16*)(qrow + off);
    frag16 b0 = *(const frag16*)(krow0 + off);
    frag16 b1 = *(const frag16*)(krow0 + (size_t)16 * HW + off);
    frag16 b2 = *(const frag16*)(krow0 + (size_t)32 * HW + off);
    frag16 b3 = *(const frag16*)(krow0 + (size_t)48 * HW + off);
    acc0 = __builtin_amdgcn_mfma_f32_16x16x32_bf16(a, b0, acc0, 0, 0, 0);
    acc1 = __builtin_amdgcn_mfma_f32_16x16x32_bf16(a, b1, acc1, 0, 0, 0);
    acc2 = __builtin_amdgcn_mfma_f32_16x16x32_bf16(a, b2, acc2, 0, 0, 0);
    acc3 = __builtin_amdgcn_mfma_f32_16x16x32_bf16(a, b3, acc3, 0, 0, 0);
  }
  // C/D layout: row(d) = (lane>>4)*4 + r, col(e) = lane&15
  float* po = part + (size_t)(bh * NCH + chunk) * 4096;
  int dr = wave * 16 + (lane >> 4) * 4;
  int e0 = lane & 15;
#pragma unroll
  for (int r = 0; r < 4; ++r) {
    po[(dr + r) * 64 +  0 + e0] = acc0[r];
    po[(dr + r) * 64 + 16 + e0] = acc1[r];
    po[(dr + r) * 64 + 32 + e0] = acc2[r];
    po[(dr + r) * 64 + 48 + e0] = acc3[r];
  }
}

// ---------------------------------------------------------------- K2r: reduce partials -> gram
__global__ void k2_reduce(const float* __restrict__ part, float* __restrict__ gram) {
  int idx = blockIdx.x * 256 + threadIdx.x;   // < 64*4096
  int bh = idx >> 12, de = idx & 4095;
  float s = 0.f;
#pragma unroll
  for (int ch = 0; ch < NCH; ++ch)
    s += part[(size_t)(bh * NCH + ch) * 4096 + de];
  gram[idx] = s;
}

// ---------------------------------------------------------------- K2b: normalize + softmax
// attn row-major [d][e], emitted as bf16 hi/lo split: hi+lo ~= attn to ~2^-17.
__global__ __launch_bounds__(64) void k2_softmax(
    const float* __restrict__ gram, bf16* __restrict__ ah, bf16* __restrict__ al,
    const float* __restrict__ qn2, const float* __restrict__ kn2,
    const float* __restrict__ t_f) {
  __shared__ float kns[64];
  int bh = blockIdx.x, d = threadIdx.x;
  const size_t base = (size_t)bh * 4096;
  kns[d] = fmaxf(sqrtf(kn2[bh * 64 + d]), 1e-12f);
  __syncthreads();
  float qn = fmaxf(sqrtf(qn2[bh * 64 + d]), 1e-12f);
  float sc = t_f[bh & 7] / qn;
  float lg[64];
  float m = -1e30f;
#pragma unroll
  for (int e = 0; e < 64; ++e) {
    lg[e] = gram[base + d * 64 + e] * sc / kns[e];
    m = fmaxf(m, lg[e]);
  }
  float s = 0.f;
#pragma unroll
  for (int e = 0; e < 64; ++e) { lg[e] = __expf(lg[e] - m); s += lg[e]; }
  float inv = 1.f / s;
#pragma unroll
  for (int e = 0; e < 64; ++e) {
    float p = lg[e] * inv;
    bf16 hi = f2b(p);
    ah[base + d * 64 + e] = hi;
    al[base + d * 64 + e] = f2b(p - b2f(hi));
  }
}

// ---------------------------------------------------------------- K3: o = attn @ v via MFMA
// block = (chunk of 256 px, bh). v tile staged in LDS [64 e][260 pad] bf16.
// A = attn_hi/lo [d][e] (frag: row m=lane&15, 8 e contiguous).
// B-frag: lane col n holds v[k8+j][n], built by 8x ds_read_u16.
// C/D: row d=(lane>>4)*4+r, col n=lane&15. o stored in fused-conv channel order.
__global__ __launch_bounds__(256) void k3_av(
    const bf16* __restrict__ ah, const bf16* __restrict__ al,
    const bf16* __restrict__ vg, bf16* __restrict__ og) {
  __shared__ unsigned short vs[64 * 260];   // 33.3 KB
  int tid = threadIdx.x;
  int wave = tid >> 6, lane = tid & 63;
  int chunk = blockIdx.x;   // 0..35 (256 pixels each)
  int bh = blockIdx.y;      // 0..63
  int b = bh >> 3, h = bh & 7;
  int n0 = chunk * 256;
  const bf16* vp = vg + (size_t)bh * HD * HW;
  // stage v[0:64][n0:n0+256] -> LDS row-major, pad 260
#pragma unroll
  for (int i = 0; i < 16; ++i) {
    int lin = i * 256 + tid;            // ushort4 units: 64 rows * 64 units
    int e = lin >> 6, c4 = lin & 63;
    ushort4 vv = *(const ushort4*)(vp + (size_t)e * HW + n0 + c4 * 4);
    *(ushort4*)&vs[e * 260 + c4 * 4] = vv;
  }
  __syncthreads();

  int m = lane & 15;
  int k8 = (lane >> 4) * 8;
  const bf16* ahp = ah + (size_t)bh * 4096;
  const bf16* alp = al + (size_t)bh * 4096;
  // preload A fragments: [dtile][khalf]
  frag16 a_hi[4][2], a_lo[4][2];
#pragma unroll
  for (int dt = 0; dt < 4; ++dt)
#pragma unroll
    for (int kh = 0; kh < 2; ++kh) {
      a_hi[dt][kh] = *(const frag16*)(ahp + (dt * 16 + m) * 64 + kh * 32 + k8);
      a_lo[dt][kh] = *(const frag16*)(alp + (dt * 16 + m) * 64 + kh * 32 + k8);
    }

  f32x4 acc[4][4];
#pragma unroll
  for (int dt = 0; dt < 4; ++dt)
#pragma unroll
    for (int nt = 0; nt < 4; ++nt) acc[dt][nt] = {0.f, 0.f, 0.f, 0.f};

  int nwbase = wave * 64;
#pragma unroll
  for (int nt = 0; nt < 4; ++nt) {
#pragma unroll
    for (int kh = 0; kh < 2; ++kh) {
      frag16 bf;
#pragma unroll
      for (int j = 0; j < 8; ++j)
        bf[j] = (short)vs[(kh * 32 + k8 + j) * 260 + nwbase + nt * 16 + m];
#pragma unroll
      for (int dt = 0; dt < 4; ++dt) {
        acc[dt][nt] = __builtin_amdgcn_mfma_f32_16x16x32_bf16(a_hi[dt][kh], bf, acc[dt][nt], 0, 0, 0);
        acc[dt][nt] = __builtin_amdgcn_mfma_f32_16x16x32_bf16(a_lo[dt][kh], bf, acc[dt][nt], 0, 0, 0);
      }
    }
  }
  // store: o channel cc = cc0 + d*4, pixel n
  int cc0 = (h & 1) * 256 + (h >> 1);
  bf16* ob = og + (size_t)b * 512 * HW;
  int q4 = (lane >> 4) * 4;
#pragma unroll
  for (int dt = 0; dt < 4; ++dt)
#pragma unroll
    for (int nt = 0; nt < 4; ++nt) {
      int n = n0 + nwbase + nt * 16 + m;
#pragma unroll
      for (int r = 0; r < 4; ++r) {
        int d = dt * 16 + q4 + r;
        ob[(size_t)(cc0 + d * 4) * HW + n] = f2b(acc[dt][nt][r]);
      }
    }
}

// ---------------------------------------------------------------- K4: fused grouped 3x3 conv (4 in-ch -> 1 out-ch)
// Tile = 24 rows. All 4 input channels staged channel-interleaved into zero-padded LDS:
// lds[row 26][col 100][ch 4]; interior col base 2. Inner loop: 9 ds_read_b128 + 36 FMA, no branches.
__global__ __launch_bounds__(256) void k4_fuse(
    const bf16* __restrict__ og, const float* __restrict__ wf,
    const float* __restrict__ bfu, float* __restrict__ out) {
  __shared__ float lds[26 * 100 * 4];   // 41.6 KB
  int tid = threadIdx.x;
  int tile = blockIdx.x;                // 0..3
  int bc = blockIdx.y;                  // 0..1023
  int b = bc >> 7, c = bc & 127;
  for (int i = tid; i < (26 * 100 * 4) / 4; i += 256)
    ((float4*)lds)[i] = make_float4(0.f, 0.f, 0.f, 0.f);
  __syncthreads();
  int r0 = tile * 24 - 1;
  const bf16* op = og + (size_t)(b * 512 + c * 4) * HW;
  for (int i = tid; i < 26 * 96; i += 256) {
    int rr = i / 96, x = i - rr * 96;
    int gr = r0 + rr;
    if (gr >= 0 && gr < 96) {
      int gp = gr * 96 + x;
      float4 vv;
      vv.x = b2f(op[gp]);
      vv.y = b2f(op[HW + gp]);
      vv.z = b2f(op[2 * HW + gp]);
      vv.w = b2f(op[(size_t)3 * HW + gp]);
      *(float4*)&lds[(rr * 100 + 2 + x) * 4] = vv;
    }
  }
  __syncthreads();
  const float* wrow = wf + c * 36;      // uniform -> s_load
  float bias = bfu[c];
  float* outp = out + (size_t)(b * CC + c) * HW + tile * 24 * 96;
#pragma unroll
  for (int pi = 0; pi < 9; ++pi) {
    int p = pi * 256 + tid;
    int ry = p / 96, x = p - ry * 96;
    float a0 = bias, a1 = 0.f, a2 = 0.f, a3 = 0.f;
#pragma unroll
    for (int ky = 0; ky < 3; ++ky)
#pragma unroll
      for (int kx = 0; kx < 3; ++kx) {
        const float4 vv = *(const float4*)&lds[((ry + ky) * 100 + 1 + x + kx) * 4];
        a0 = fmaf(wrow[0 + ky * 3 + kx],  vv.x, a0);
        a1 = fmaf(wrow[9 + ky * 3 + kx],  vv.y, a1);
        a2 = fmaf(wrow[18 + ky * 3 + kx], vv.z, a2);
        a3 = fmaf(wrow[27 + ky * 3 + kx], vv.w, a3);
      }
    outp[p] = (a0 + a1) + (a2 + a3);
  }
}

// ---------------------------------------------------------------- launcher
extern "C" void kernel_launch(void* const* d_in, const int* in_sizes, int n_in,
                              void* d_out, int out_size, void* d_ws, size_t ws_size,
                              hipStream_t stream) {
  (void)in_sizes; (void)n_in; (void)out_size; (void)ws_size;
  const float* x   = (const float*)d_in[0];
  const float* wq  = (const float*)d_in[1];
  const float* bq  = (const float*)d_in[2];
  const float* tt  = (const float*)d_in[3];
  const float* wf  = (const float*)d_in[4];
  const float* bfu = (const float*)d_in[5];

  // workspace layout (~246 MB)
  char* ws = (char*)d_ws;
  bf16*  qg    = (bf16*)(ws + 0);                 // 75497472 B, later aliased by og
  bf16*  kg    = (bf16*)(ws + 75497472);          // 75497472 B
  bf16*  vg    = (bf16*)(ws + 150994944);         // 75497472 B
  float* part  = (float*)(ws + 226492416);        // 16777216 B
  float* gram  = (float*)(ws + 243269632);        // 1048576 B
  bf16*  ah    = (bf16*)(ws + 244318208);         // 524288 B
  bf16*  al    = (bf16*)(ws + 244842496);         // 524288 B
  float* qn2   = (float*)(ws + 245366784);        // 16384 B
  float* kn2   = (float*)(ws + 245383168);        // 16384 B
  bf16*  og    = qg;                              // q is dead after k2_gram
  float* out   = (float*)d_out;

  hipLaunchKernelGGL(k1_qkv, dim3(1024), dim3(256), 0, stream,
                     x, wq, bq, qg, kg, vg, qn2, kn2);
  hipLaunchKernelGGL(k2_gram, dim3(NCH, 64), dim3(256), 0, stream, qg, kg, part);
  hipLaunchKernelGGL(k2_reduce, dim3(1024), dim3(256), 0, stream, part, gram);
  hipLaunchKernelGGL(k2_softmax, dim3(64), dim3(64), 0, stream,
                     gram, ah, al, qn2, kn2, tt);
  hipLaunchKernelGGL(k3_av, dim3(36, 64), dim3(256), 0, stream, ah, al, vg, og);
  hipLaunchKernelGGL(k4_fuse, dim3(4, 1024), dim3(256), 0, stream, og, wf, bfu, out);
}

// Round 5
// 302.110 us; speedup vs baseline: 2.0989x; 1.0958x over previous
//
#include <hip/hip_runtime.h>
#include <hip/hip_bf16.h>
#include <stdint.h>

// Problem constants
#define BB     8
#define CC     128
#define HW     9216      // 96*96
#define NHEAD  8
#define HD     64
#define NCH    16        // gram n-chunks
#define CHUNK  576       // HW/NCH

typedef __hip_bfloat16 bf16;
using frag16 = __attribute__((ext_vector_type(8))) short;  // 8 bf16 (4 VGPRs)
using f32x4  = __attribute__((ext_vector_type(4))) float;

__device__ __forceinline__ float b2f(bf16 v) { return __bfloat162float(v); }
__device__ __forceinline__ bf16  f2b(float v) { return __float2bfloat16(v); }
__device__ __forceinline__ float us2f(unsigned short u) {
  return __uint_as_float(((unsigned int)u) << 16);
}
__device__ __forceinline__ unsigned short f2us(float v) {
  bf16 h = f2b(v);
  return *(unsigned short*)&h;
}

// ---------------------------------------------------------------- K1: qkv depthwise conv + q/k norm sums
// block = (b, c). conv out channel oc = c*12 + j; j in [0,4)=q(e=j), [4,8)=k, [8,12)=v.
// head h = e*2 + c/64, row d = c%64. Stores q,k,v bf16 as [b, h, d_or_e, n].
// 4 pixels/thread: per row one aligned ds_read_b128 + 2 ds_read_b32; ushort4 stores.
__global__ __launch_bounds__(256) void k1_qkv(
    const float* __restrict__ x, const float* __restrict__ wq,
    const float* __restrict__ bq,
    bf16* __restrict__ qg, bf16* __restrict__ kg, bf16* __restrict__ vg,
    float* __restrict__ qn2, float* __restrict__ kn2) {
  __shared__ float xs[98 * 104];    // 40.8 KB, zero-padded halo; interior col base 4
  __shared__ float red[32];
  int tid = threadIdx.x;
  int wave = tid >> 6, lane = tid & 63;
  int b = blockIdx.x >> 7, c = blockIdx.x & 127;
  const float* xp = x + (size_t)(b * CC + c) * HW;
  // zero everything (covers borders), then fill interior
  for (int i = tid; i < (98 * 104) / 4; i += 256)
    ((float4*)xs)[i] = make_float4(0.f, 0.f, 0.f, 0.f);
  __syncthreads();
  for (int i = tid; i < 96 * 24; i += 256) {
    int y = i / 24, k4i = i - y * 24;
    ((float4*)(xs + (y + 1) * 104 + 4))[k4i] = ((const float4*)(xp + y * 96))[k4i];
  }
  __syncthreads();

  int half = c >> 6, d = c & 63;
  int nidx[8];
  size_t basep[12];
#pragma unroll
  for (int j = 0; j < 12; ++j) {
    int e = j & 3;                       // j%4 within each q/k/v group
    int h = e * 2 + half;
    int ni = (b * NHEAD + h) * HD + d;
    if (j < 8) nidx[j] = ni;
    basep[j] = (size_t)ni * HW;
  }
  const float* wrow = wq + c * 108;      // 12 channels * 9 taps, uniform -> s_load
  const float* brow = bq + c * 12;

  float ssq[8];
#pragma unroll
  for (int j = 0; j < 8; ++j) ssq[j] = 0.f;

#pragma unroll 1
  for (int it = 0; it < 9; ++it) {
    int q4i = it * 256 + tid;
    int p0 = q4i * 4;                    // 4-px group, never crosses a row (96 % 4 == 0)
    int y = q4i / 24;                    // p0 / 96
    int xx = p0 - y * 96;
    // 3 rows x 6 cols into registers
    float w6[3][6];
#pragma unroll
    for (int ky = 0; ky < 3; ++ky) {
      int basea = (y + ky) * 104 + 4 + xx;   // 16B-aligned (xx % 4 == 0)
      float4 M = *(const float4*)&xs[basea];
      w6[ky][0] = xs[basea - 1];
      w6[ky][1] = M.x; w6[ky][2] = M.y; w6[ky][3] = M.z; w6[ky][4] = M.w;
      w6[ky][5] = xs[basea + 4];
    }
#pragma unroll
    for (int j = 0; j < 12; ++j) {
      float bias = brow[j];
      float a0 = bias, a1 = bias, a2 = bias, a3 = bias;
#pragma unroll
      for (int ky = 0; ky < 3; ++ky)
#pragma unroll
        for (int kx = 0; kx < 3; ++kx) {
          float w = wrow[j * 9 + ky * 3 + kx];
          a0 = fmaf(w, w6[ky][kx + 0], a0);
          a1 = fmaf(w, w6[ky][kx + 1], a1);
          a2 = fmaf(w, w6[ky][kx + 2], a2);
          a3 = fmaf(w, w6[ky][kx + 3], a3);
        }
      ushort4 st;
      st.x = f2us(a0); st.y = f2us(a1); st.z = f2us(a2); st.w = f2us(a3);
      if (j < 4)      *(ushort4*)(qg + basep[j] + p0) = st;
      else if (j < 8) *(ushort4*)(kg + basep[j] + p0) = st;
      else            *(ushort4*)(vg + basep[j] + p0) = st;
      if (j < 8) {
        float v0 = us2f(st.x), v1 = us2f(st.y), v2 = us2f(st.z), v3 = us2f(st.w);
        ssq[j] += v0 * v0 + v1 * v1 + v2 * v2 + v3 * v3;
      }
    }
  }
  // wave shuffle-reduce the 8 sums, then one LDS combine across the 4 waves
#pragma unroll
  for (int j = 0; j < 8; ++j) {
    float v = ssq[j];
#pragma unroll
    for (int off = 32; off > 0; off >>= 1) v += __shfl_down(v, off);
    if (lane == 0) red[wave * 8 + j] = v;
  }
  __syncthreads();
  if (tid < 8) {
    float s = red[tid] + red[8 + tid] + red[16 + tid] + red[24 + tid];
    if (tid < 4) qn2[nidx[tid]] = s;
    else         kn2[nidx[tid]] = s;
  }
}

// ---------------------------------------------------------------- K2a: gram partials via MFMA
// part[bh][chunk][d][e] += q[d][n]*k[e][n] over the chunk. A=qg rows, B^T=kg rows.
__global__ __launch_bounds__(256) void k2_gram(
    const bf16* __restrict__ qg, const bf16* __restrict__ kg,
    float* __restrict__ part) {
  int tid = threadIdx.x;
  int wave = tid >> 6;           // 0..3 -> d-tile
  int lane = tid & 63;
  int chunk = blockIdx.x;        // 0..15
  int bh = blockIdx.y;           // 0..63
  const size_t base = (size_t)bh * HD * HW;
  int m = lane & 15;
  int k8 = (lane >> 4) * 8;
  const bf16* qrow  = qg + base + (size_t)(wave * 16 + m) * HW + k8;
  const bf16* krow0 = kg + base + (size_t)m * HW + k8;
  f32x4 acc0 = {0.f, 0.f, 0.f, 0.f}, acc1 = acc0, acc2 = acc0, acc3 = acc0;
  for (int kb = 0; kb < CHUNK; kb += 32) {
    int off = chunk * CHUNK + kb;
    frag16 a  = *(const frag16*)(qrow + off);
    frag16 b0 = *(const frag16*)(krow0 + off);
    frag16 b1 = *(const frag16*)(krow0 + (size_t)16 * HW + off);
    frag16 b2 = *(const frag16*)(krow0 + (size_t)32 * HW + off);
    frag16 b3 = *(const frag16*)(krow0 + (size_t)48 * HW + off);
    acc0 = __builtin_amdgcn_mfma_f32_16x16x32_bf16(a, b0, acc0, 0, 0, 0);
    acc1 = __builtin_amdgcn_mfma_f32_16x16x32_bf16(a, b1, acc1, 0, 0, 0);
    acc2 = __builtin_amdgcn_mfma_f32_16x16x32_bf16(a, b2, acc2, 0, 0, 0);
    acc3 = __builtin_amdgcn_mfma_f32_16x16x32_bf16(a, b3, acc3, 0, 0, 0);
  }
  // C/D layout: row(d) = (lane>>4)*4 + r, col(e) = lane&15
  float* po = part + (size_t)(bh * NCH + chunk) * 4096;
  int dr = wave * 16 + (lane >> 4) * 4;
  int e0 = lane & 15;
#pragma unroll
  for (int r = 0; r < 4; ++r) {
    po[(dr + r) * 64 +  0 + e0] = acc0[r];
    po[(dr + r) * 64 + 16 + e0] = acc1[r];
    po[(dr + r) * 64 + 32 + e0] = acc2[r];
    po[(dr + r) * 64 + 48 + e0] = acc3[r];
  }
}

// ---------------------------------------------------------------- K2r: reduce partials -> gram
__global__ void k2_reduce(const float* __restrict__ part, float* __restrict__ gram) {
  int idx = blockIdx.x * 256 + threadIdx.x;   // < 64*4096
  int bh = idx >> 12, de = idx & 4095;
  float s = 0.f;
#pragma unroll
  for (int ch = 0; ch < NCH; ++ch)
    s += part[(size_t)(bh * NCH + ch) * 4096 + de];
  gram[idx] = s;
}

// ---------------------------------------------------------------- K2b: normalize + softmax
// attn row-major [d][e], emitted as bf16 hi/lo split: hi+lo ~= attn to ~2^-17.
__global__ __launch_bounds__(64) void k2_softmax(
    const float* __restrict__ gram, bf16* __restrict__ ah, bf16* __restrict__ al,
    const float* __restrict__ qn2, const float* __restrict__ kn2,
    const float* __restrict__ t_f) {
  __shared__ float kns[64];
  int bh = blockIdx.x, d = threadIdx.x;
  const size_t base = (size_t)bh * 4096;
  kns[d] = fmaxf(sqrtf(kn2[bh * 64 + d]), 1e-12f);
  __syncthreads();
  float qn = fmaxf(sqrtf(qn2[bh * 64 + d]), 1e-12f);
  float sc = t_f[bh & 7] / qn;
  float lg[64];
  float m = -1e30f;
#pragma unroll
  for (int e = 0; e < 64; ++e) {
    lg[e] = gram[base + d * 64 + e] * sc / kns[e];
    m = fmaxf(m, lg[e]);
  }
  float s = 0.f;
#pragma unroll
  for (int e = 0; e < 64; ++e) { lg[e] = __expf(lg[e] - m); s += lg[e]; }
  float inv = 1.f / s;
#pragma unroll
  for (int e = 0; e < 64; ++e) {
    float p = lg[e] * inv;
    bf16 hi = f2b(p);
    ah[base + d * 64 + e] = hi;
    al[base + d * 64 + e] = f2b(p - b2f(hi));
  }
}

// ---------------------------------------------------------------- K3: o = attn @ v via MFMA
// block = (chunk of 256 px, bh). v tile staged in LDS [64 e][260 pad] bf16.
__global__ __launch_bounds__(256) void k3_av(
    const bf16* __restrict__ ah, const bf16* __restrict__ al,
    const bf16* __restrict__ vg, bf16* __restrict__ og) {
  __shared__ unsigned short vs[64 * 260];   // 33.3 KB
  int tid = threadIdx.x;
  int wave = tid >> 6, lane = tid & 63;
  int chunk = blockIdx.x;   // 0..35 (256 pixels each)
  int bh = blockIdx.y;      // 0..63
  int b = bh >> 3, h = bh & 7;
  int n0 = chunk * 256;
  const bf16* vp = vg + (size_t)bh * HD * HW;
#pragma unroll
  for (int i = 0; i < 16; ++i) {
    int lin = i * 256 + tid;            // ushort4 units: 64 rows * 64 units
    int e = lin >> 6, c4 = lin & 63;
    ushort4 vv = *(const ushort4*)(vp + (size_t)e * HW + n0 + c4 * 4);
    *(ushort4*)&vs[e * 260 + c4 * 4] = vv;
  }
  __syncthreads();

  int m = lane & 15;
  int k8 = (lane >> 4) * 8;
  const bf16* ahp = ah + (size_t)bh * 4096;
  const bf16* alp = al + (size_t)bh * 4096;
  frag16 a_hi[4][2], a_lo[4][2];
#pragma unroll
  for (int dt = 0; dt < 4; ++dt)
#pragma unroll
    for (int kh = 0; kh < 2; ++kh) {
      a_hi[dt][kh] = *(const frag16*)(ahp + (dt * 16 + m) * 64 + kh * 32 + k8);
      a_lo[dt][kh] = *(const frag16*)(alp + (dt * 16 + m) * 64 + kh * 32 + k8);
    }

  f32x4 acc[4][4];
#pragma unroll
  for (int dt = 0; dt < 4; ++dt)
#pragma unroll
    for (int nt = 0; nt < 4; ++nt) acc[dt][nt] = {0.f, 0.f, 0.f, 0.f};

  int nwbase = wave * 64;
#pragma unroll
  for (int nt = 0; nt < 4; ++nt) {
#pragma unroll
    for (int kh = 0; kh < 2; ++kh) {
      frag16 bf;
#pragma unroll
      for (int j = 0; j < 8; ++j)
        bf[j] = (short)vs[(kh * 32 + k8 + j) * 260 + nwbase + nt * 16 + m];
#pragma unroll
      for (int dt = 0; dt < 4; ++dt) {
        acc[dt][nt] = __builtin_amdgcn_mfma_f32_16x16x32_bf16(a_hi[dt][kh], bf, acc[dt][nt], 0, 0, 0);
        acc[dt][nt] = __builtin_amdgcn_mfma_f32_16x16x32_bf16(a_lo[dt][kh], bf, acc[dt][nt], 0, 0, 0);
      }
    }
  }
  int cc0 = (h & 1) * 256 + (h >> 1);
  bf16* ob = og + (size_t)b * 512 * HW;
  int q4 = (lane >> 4) * 4;
#pragma unroll
  for (int dt = 0; dt < 4; ++dt)
#pragma unroll
    for (int nt = 0; nt < 4; ++nt) {
      int n = n0 + nwbase + nt * 16 + m;
#pragma unroll
      for (int r = 0; r < 4; ++r) {
        int d = dt * 16 + q4 + r;
        ob[(size_t)(cc0 + d * 4) * HW + n] = f2b(acc[dt][nt][r]);
      }
    }
}

// ---------------------------------------------------------------- K4: fused grouped 3x3 conv (4 in-ch -> 1 out-ch)
__global__ __launch_bounds__(256) void k4_fuse(
    const bf16* __restrict__ og, const float* __restrict__ wf,
    const float* __restrict__ bfu, float* __restrict__ out) {
  __shared__ float lds[26 * 100 * 4];   // 41.6 KB
  int tid = threadIdx.x;
  int tile = blockIdx.x;                // 0..3
  int bc = blockIdx.y;                  // 0..1023
  int b = bc >> 7, c = bc & 127;
  for (int i = tid; i < (26 * 100 * 4) / 4; i += 256)
    ((float4*)lds)[i] = make_float4(0.f, 0.f, 0.f, 0.f);
  __syncthreads();
  int r0 = tile * 24 - 1;
  const bf16* op = og + (size_t)(b * 512 + c * 4) * HW;
  for (int i = tid; i < 26 * 96; i += 256) {
    int rr = i / 96, x = i - rr * 96;
    int gr = r0 + rr;
    if (gr >= 0 && gr < 96) {
      int gp = gr * 96 + x;
      float4 vv;
      vv.x = b2f(op[gp]);
      vv.y = b2f(op[HW + gp]);
      vv.z = b2f(op[2 * HW + gp]);
      vv.w = b2f(op[(size_t)3 * HW + gp]);
      *(float4*)&lds[(rr * 100 + 2 + x) * 4] = vv;
    }
  }
  __syncthreads();
  const float* wrow = wf + c * 36;      // uniform -> s_load
  float bias = bfu[c];
  float* outp = out + (size_t)(b * CC + c) * HW + tile * 24 * 96;
#pragma unroll
  for (int pi = 0; pi < 9; ++pi) {
    int p = pi * 256 + tid;
    int ry = p / 96, x = p - ry * 96;
    float a0 = bias, a1 = 0.f, a2 = 0.f, a3 = 0.f;
#pragma unroll
    for (int ky = 0; ky < 3; ++ky)
#pragma unroll
      for (int kx = 0; kx < 3; ++kx) {
        const float4 vv = *(const float4*)&lds[((ry + ky) * 100 + 1 + x + kx) * 4];
        a0 = fmaf(wrow[0 + ky * 3 + kx],  vv.x, a0);
        a1 = fmaf(wrow[9 + ky * 3 + kx],  vv.y, a1);
        a2 = fmaf(wrow[18 + ky * 3 + kx], vv.z, a2);
        a3 = fmaf(wrow[27 + ky * 3 + kx], vv.w, a3);
      }
    outp[p] = (a0 + a1) + (a2 + a3);
  }
}

// ---------------------------------------------------------------- launcher
extern "C" void kernel_launch(void* const* d_in, const int* in_sizes, int n_in,
                              void* d_out, int out_size, void* d_ws, size_t ws_size,
                              hipStream_t stream) {
  (void)in_sizes; (void)n_in; (void)out_size; (void)ws_size;
  const float* x   = (const float*)d_in[0];
  const float* wq  = (const float*)d_in[1];
  const float* bq  = (const float*)d_in[2];
  const float* tt  = (const float*)d_in[3];
  const float* wf  = (const float*)d_in[4];
  const float* bfu = (const float*)d_in[5];

  // workspace layout (~246 MB)
  char* ws = (char*)d_ws;
  bf16*  qg    = (bf16*)(ws + 0);                 // 75497472 B, later aliased by og
  bf16*  kg    = (bf16*)(ws + 75497472);          // 75497472 B
  bf16*  vg    = (bf16*)(ws + 150994944);         // 75497472 B
  float* part  = (float*)(ws + 226492416);        // 16777216 B
  float* gram  = (float*)(ws + 243269632);        // 1048576 B
  bf16*  ah    = (bf16*)(ws + 244318208);         // 524288 B
  bf16*  al    = (bf16*)(ws + 244842496);         // 524288 B
  float* qn2   = (float*)(ws + 245366784);        // 16384 B
  float* kn2   = (float*)(ws + 245383168);        // 16384 B
  bf16*  og    = qg;                              // q is dead after k2_gram
  float* out   = (float*)d_out;

  hipLaunchKernelGGL(k1_qkv, dim3(1024), dim3(256), 0, stream,
                     x, wq, bq, qg, kg, vg, qn2, kn2);
  hipLaunchKernelGGL(k2_gram, dim3(NCH, 64), dim3(256), 0, stream, qg, kg, part);
  hipLaunchKernelGGL(k2_reduce, dim3(1024), dim3(256), 0, stream, part, gram);
  hipLaunchKernelGGL(k2_softmax, dim3(64), dim3(64), 0, stream,
                     gram, ah, al, qn2, kn2, tt);
  hipLaunchKernelGGL(k3_av, dim3(36, 64), dim3(256), 0, stream, ah, al, vg, og);
  hipLaunchKernelGGL(k4_fuse, dim3(4, 1024), dim3(256), 0, stream, og, wf, bfu, out);
}